// Round 10
// baseline (462.628 us; speedup 1.0000x reference)
//
#include <hip/hip_runtime.h>
#include <math.h>

#define B_ 4
#define T_ 2048
#define D_ 256
#define H_ 4
#define DH_ 64
#define INNER_ 512
#define FFI_ 1024

typedef unsigned short u16;
typedef __bf16 bhalf;
typedef bhalf bhalf8 __attribute__((ext_vector_type(8)));
typedef float floatx4 __attribute__((ext_vector_type(4)));

__device__ __forceinline__ float lrelu(float x){ return x >= 0.f ? x : 0.3f * x; }

__device__ __forceinline__ u16 f2b(float f){
    unsigned u = __float_as_uint(f);
    return (u16)((u + 0x7fffu + ((u >> 16) & 1u)) >> 16);
}
// round-half-up bf16 (2 VALU ops) for hot inner-loop stores
__device__ __forceinline__ u16 f2b_fast(float f){
    return (u16)((__float_as_uint(f) + 0x8000u) >> 16);
}
__device__ __forceinline__ float b2f(u16 v){ return __uint_as_float((unsigned)v << 16); }

__device__ __forceinline__ void gload16(const void* g, void* l){
    __builtin_amdgcn_global_load_lds(
        (const __attribute__((address_space(1))) unsigned*)g,
        (__attribute__((address_space(3))) unsigned*)l, 16, 0, 0);
}

// ---- DPP 16-lane rotate-reduce (row_ror:1/2/4/8) ----
__device__ __forceinline__ float dpp16_add(float x){
    int t;
    t = __builtin_amdgcn_update_dpp(0, __float_as_int(x), 0x121, 0xf, 0xf, false); x += __int_as_float(t);
    t = __builtin_amdgcn_update_dpp(0, __float_as_int(x), 0x122, 0xf, 0xf, false); x += __int_as_float(t);
    t = __builtin_amdgcn_update_dpp(0, __float_as_int(x), 0x124, 0xf, 0xf, false); x += __int_as_float(t);
    t = __builtin_amdgcn_update_dpp(0, __float_as_int(x), 0x128, 0xf, 0xf, false); x += __int_as_float(t);
    return x;
}
__device__ __forceinline__ float dpp16_max(float x){
    int t;
    t = __builtin_amdgcn_update_dpp(0, __float_as_int(x), 0x121, 0xf, 0xf, false); x = fmaxf(x, __int_as_float(t));
    t = __builtin_amdgcn_update_dpp(0, __float_as_int(x), 0x122, 0xf, 0xf, false); x = fmaxf(x, __int_as_float(t));
    t = __builtin_amdgcn_update_dpp(0, __float_as_int(x), 0x124, 0xf, 0xf, false); x = fmaxf(x, __int_as_float(t));
    t = __builtin_amdgcn_update_dpp(0, __float_as_int(x), 0x128, 0xf, 0xf, false); x = fmaxf(x, __int_as_float(t));
    return x;
}

// ---------------- weight/activation cast kernels ----------------
__global__ __launch_bounds__(256) void cast4_kernel(
        const float* __restrict__ s0, u16* d0, int n0_,
        const float* __restrict__ s1, u16* d1, int n1_,
        const float* __restrict__ s2, u16* d2, int n2_,
        const float* __restrict__ s3, u16* d3, int n3_){
    int idx = blockIdx.x * 256 + threadIdx.x;
    int y = blockIdx.y;
    const float* s = y==0 ? s0 : y==1 ? s1 : y==2 ? s2 : s3;
    u16* d        = y==0 ? d0 : y==1 ? d1 : y==2 ? d2 : d3;
    int n         = y==0 ? n0_ : y==1 ? n1_ : y==2 ? n2_ : n3_;
    if (idx < n) d[idx] = f2b(s[idx]);
}

__global__ __launch_bounds__(256) void castT5_kernel(
        const float* __restrict__ s0, const float* __restrict__ s1,
        const float* __restrict__ s2, const float* __restrict__ s3,
        const float* __restrict__ s4,
        u16* d0, u16* d1, u16* d2, u16* d3, u16* d4){
    int idx = blockIdx.x * 256 + threadIdx.x;
    int y = blockIdx.y;
    const float* s = y==0 ? s0 : y==1 ? s1 : y==2 ? s2 : y==3 ? s3 : s4;
    u16* d        = y==0 ? d0 : y==1 ? d1 : y==2 ? d2 : y==3 ? d3 : d4;
    int n = idx >> 8, k = idx & 255;
    d[idx] = f2b(s[k * 256 + n]);
}

__global__ __launch_bounds__(256) void castFF1_kernel(const float* __restrict__ s, u16* d){
    int idx = blockIdx.x * 256 + threadIdx.x;
    int n = idx / 768, rem = idx - n * 768;
    int kc = rem >> 8, c = rem & 255;
    d[idx] = f2b(s[(n * 256 + c) * 3 + kc]);
}

// ---------------- LayerNorm: one wave per 256-elem row ----------------
__global__ __launch_bounds__(256) void ln_kernel(const float* __restrict__ x,
        const float* __restrict__ g, const float* __restrict__ b,
        u16* __restrict__ out){
    int wave = threadIdx.x >> 6, lane = threadIdx.x & 63;
    int row = blockIdx.x * 4 + wave;
    size_t base = (size_t)row * D_ + lane * 4;
    float4 v = *(const float4*)(x + base);
    float s = v.x + v.y + v.z + v.w;
    #pragma unroll
    for (int mk = 1; mk < 64; mk <<= 1) s += __shfl_xor(s, mk, 64);
    float mean = s * (1.f / D_);
    float4 d = make_float4(v.x - mean, v.y - mean, v.z - mean, v.w - mean);
    float q = d.x*d.x + d.y*d.y + d.z*d.z + d.w*d.w;
    #pragma unroll
    for (int mk = 1; mk < 64; mk <<= 1) q += __shfl_xor(q, mk, 64);
    float rs = rsqrtf(q * (1.f / D_) + 1e-5f);
    float4 gg = *(const float4*)(g + lane * 4);
    float4 bb = *(const float4*)(b + lane * 4);
    ushort4 o;
    o.x = f2b(d.x * rs * gg.x + bb.x);
    o.y = f2b(d.y * rs * gg.y + bb.y);
    o.z = f2b(d.z * rs * gg.z + bb.z);
    o.w = f2b(d.w * rs * gg.w + bb.w);
    *(ushort4*)(out + base) = o;
}

// ================= bf16 MFMA GEMM, BN = 128 or 64 =================
template<int BN, int AMODE, bool BIAS, bool ACT, bool RES, bool OUTBF>
__global__ __launch_bounds__(256) void gemm_bf(
        const u16* __restrict__ A, const u16* __restrict__ Bw,
        const float* __restrict__ bias, const float* __restrict__ res,
        void* __restrict__ C, int M, int N, int K, float alpha,
        const u16* __restrict__ zbuf){
    __shared__ __align__(16) u16 As[128 * 32];
    __shared__ __align__(16) u16 Bs[BN * 32];
    const int tid = threadIdx.x;
    const int lane = tid & 63, w = tid >> 6;
    const int ln15 = lane & 15, quad = lane >> 4;
    const int m0 = blockIdx.y * 128, n0 = blockIdx.x * BN;
    const int lrow = lane >> 2, lcol = (lane & 3) * 8;
    const int MT = (BN == 128) ? 4 : 2;
    const int NT = 4;
    const int wm = (BN == 128) ? (w >> 1) : w;
    const int wn = (BN == 128) ? (w & 1) : 0;
    const int mbase = (BN == 128) ? wm * 64 : wm * 32;
    const int nbase = (BN == 128) ? wn * 64 : 0;

    floatx4 acc[4][4];
    #pragma unroll
    for (int i = 0; i < 4; i++)
        #pragma unroll
        for (int j = 0; j < 4; j++)
            acc[i][j] = (floatx4){0.f, 0.f, 0.f, 0.f};

    for (int k0 = 0; k0 < K; k0 += 32){
        __syncthreads();
        #pragma unroll
        for (int j = 0; j < 2; j++){
            int mrow = m0 + w * 32 + j * 16 + lrow;
            const u16* ga;
            if (AMODE == 0){
                ga = A + (size_t)mrow * K + k0 + lcol;
            } else {
                int bb = mrow >> 11, t = mrow & (T_ - 1);
                int kc = k0 >> 8;
                int c = (k0 & 255) + lcol;
                int t2 = t + kc - 1;
                ga = ((unsigned)t2 < (unsigned)T_)
                     ? A + ((size_t)(bb * T_ + t2)) * D_ + c : zbuf;
            }
            gload16(ga, &As[(w * 32 + j * 16) * 32]);
        }
        if (BN == 128){
            #pragma unroll
            for (int j = 0; j < 2; j++){
                const u16* gb = Bw + (size_t)(n0 + w * 32 + j * 16 + lrow) * K + k0 + lcol;
                gload16(gb, &Bs[(w * 32 + j * 16) * 32]);
            }
        } else {
            const u16* gb = Bw + (size_t)(n0 + w * 16 + lrow) * K + k0 + lcol;
            gload16(gb, &Bs[(w * 16) * 32]);
        }
        __syncthreads();
        bhalf8 af[4], bfr[4];
        #pragma unroll
        for (int mi = 0; mi < MT; mi++)
            af[mi] = *(const bhalf8*)&As[(mbase + mi * 16 + ln15) * 32 + quad * 8];
        #pragma unroll
        for (int ni = 0; ni < NT; ni++)
            bfr[ni] = *(const bhalf8*)&Bs[(nbase + ni * 16 + ln15) * 32 + quad * 8];
        #pragma unroll
        for (int mi = 0; mi < MT; mi++)
            #pragma unroll
            for (int ni = 0; ni < NT; ni++)
                acc[mi][ni] = __builtin_amdgcn_mfma_f32_16x16x32_bf16(
                    af[mi], bfr[ni], acc[mi][ni], 0, 0, 0);
    }
    #pragma unroll
    for (int mi = 0; mi < MT; mi++){
        #pragma unroll
        for (int ni = 0; ni < NT; ni++){
            int n = n0 + nbase + ni * 16 + ln15;
            float bv = BIAS ? bias[n] : 0.f;
            #pragma unroll
            for (int r = 0; r < 4; r++){
                int m = m0 + mbase + mi * 16 + quad * 4 + r;
                float val = acc[mi][ni][r] + bv;
                if (ACT) val = lrelu(val);
                if (RES) val = res[(size_t)m * N + n] + alpha * val;
                if (OUTBF) ((u16*)C)[(size_t)m * N + n] = f2b(val);
                else       ((float*)C)[(size_t)m * N + n] = val;
            }
        }
    }
}

// ---------------- V transpose: qkv[:,512+..] [B*T][768] -> vbT [B][256][T] ----------------
__global__ __launch_bounds__(256) void vT_kernel(const u16* __restrict__ qkv, u16* __restrict__ vbT){
    __shared__ u16 tile[64 * 68];
    int t0 = blockIdx.x * 64, d0 = blockIdx.y * 64, b = blockIdx.z;
    int tid = threadIdx.x;
    for (int u = tid; u < 512; u += 256){
        int r = u >> 3, c8 = (u & 7) * 8;
        *(float4*)&tile[r * 68 + c8] =
            *(const float4*)(qkv + ((size_t)(b * T_ + t0 + r)) * 768 + 512 + d0 + c8);
    }
    __syncthreads();
    for (int u = tid; u < 512; u += 256){
        int d = u >> 3, t8 = (u & 7) * 8;
        u16 g[8];
        #pragma unroll
        for (int j = 0; j < 8; j++) g[j] = tile[(t8 + j) * 68 + d];
        *(float4*)(vbT + ((size_t)(b * 256 + d0 + d)) * T_ + t0 + t8) = *(float4*)g;
    }
}

// ================= 128-row q-tile split-K pipelined MFMA flash attention =================
// Grid (T/128, B*H, 2). Wave w owns q rows [32w,32w+32) as 2 A-frags.
// Band: pp(i,j') = band[j'-i+127] over 192 zero-padded pos rows;
// jbaseA = T-128+diff (q[t]+v), jbaseB = diff-129 (q[t+1]+v); regimes self-mask.
// Per A-frag a: band n-tiles ntlo(a)=7-2w-a .. +4 (5 tiles). 1/16 folded into Q frags.
__global__ __launch_bounds__(256, 2) void attn8_kernel(
        const u16* __restrict__ qkv, const u16* __restrict__ vbT,
        const u16* __restrict__ posb,
        const float* __restrict__ ub, const float* __restrict__ vbias,
        float* __restrict__ Op, float* __restrict__ ml)
{
    __shared__ __align__(16) u16 Ks[64 * 72];      // K[s][d]
    __shared__ __align__(16) u16 Vs[64 * 72];      // V^T[d][s]
    __shared__ __align__(16) u16 Pos[192 * 72];    // pos band rows
    __shared__ __align__(16) u16 Pb[4 * 32 * 90];  // per-wave band strip / probs

    const int tid = threadIdx.x;
    const int lane = tid & 63, w = tid >> 6;
    const int ln15 = lane & 15, quad = lane >> 4;
    const int t0 = blockIdx.x * 128;
    const int bh = blockIdx.y, b = bh >> 2, h = bh & 3;
    const int z = blockIdx.z;
    const u16* qg = qkv + (size_t)b * T_ * 768 + h * DH_;
    const u16* kg = qkv + (size_t)b * T_ * 768 + 256 + h * DH_;
    const u16* vtg = vbT + ((size_t)(b * 256 + h * DH_)) * T_;
    const u16* pg = posb + h * DH_;

    // ---- register Q fragments, 1/16 pre-scaled ----
    bhalf8 quf[2][2], qvf0[2][2], qvf1[2][2];
    #pragma unroll
    for (int a = 0; a < 2; a++){
        int qrow = t0 + w * 32 + a * 16 + ln15;
        bool okn = (qrow + 1 < T_);
        #pragma unroll
        for (int ks = 0; ks < 2; ks++){
            int dof = ks * 32 + quad * 8;
            u16 q8[8], q8n[8] = {0,0,0,0,0,0,0,0};
            *(float4*)q8 = *(const float4*)(qg + (size_t)qrow * 768 + dof);
            if (okn) *(float4*)q8n = *(const float4*)(qg + (size_t)(qrow + 1) * 768 + dof);
            u16 ra[8], c0[8], c1[8];
            #pragma unroll
            for (int j = 0; j < 8; j++){
                float uu = ub[h * DH_ + dof + j];
                float vv = vbias[h * DH_ + dof + j];
                float qf = b2f(q8[j]), qf1 = okn ? b2f(q8n[j]) : 0.f;
                ra[j] = f2b((qf + uu) * 0.0625f);
                c0[j] = f2b((qf + vv) * 0.0625f);
                c1[j] = f2b((qf1 + vv) * 0.0625f);
            }
            quf[a][ks]  = *(bhalf8*)ra;
            qvf0[a][ks] = *(bhalf8*)c0;
            qvf1[a][ks] = *(bhalf8*)c1;
        }
    }

    floatx4 O[2][4];
    float m_r[2][4], l_r[2][4];
    #pragma unroll
    for (int a = 0; a < 2; a++)
        #pragma unroll
        for (int r = 0; r < 4; r++){
            O[a][r] = (floatx4){0.f,0.f,0.f,0.f};
            m_r[a][r] = -INFINITY; l_r[a][r] = 0.f;
        }

    u16* pbw = Pb + w * 32 * 90;
    const int srow = tid >> 3, sd8 = (tid & 7) * 8;

    float4 kpre[2], vpre[2], ppre[6];
    int s0 = z * (T_ / 2);
    {   // prologue prefetch
        int diff = s0 - t0;
        int jb1 = (diff <= 64) ? (T_ - 128 + diff) : (diff - 129);
        #pragma unroll
        for (int j = 0; j < 2; j++)
            kpre[j] = *(const float4*)(kg + (size_t)(s0 + srow + j * 32) * 768 + sd8);
        #pragma unroll
        for (int j = 0; j < 6; j++){
            int jj = jb1 + srow + j * 32;
            ppre[j] = ((unsigned)jj < (unsigned)T_)
                      ? *(const float4*)(pg + (size_t)jj * D_ + sd8)
                      : make_float4(0.f,0.f,0.f,0.f);
        }
        #pragma unroll
        for (int j = 0; j < 2; j++)
            vpre[j] = *(const float4*)(vtg + (size_t)(srow + j * 32) * T_ + s0 + sd8);
    }

    for (int it = 0; it < 16; it++, s0 += 64){
        int diff = s0 - t0;
        bool doA = (diff <= 64), doB = (diff >= 0);
        #pragma unroll
        for (int j = 0; j < 2; j++)
            *(float4*)&Ks[(srow + j * 32) * 72 + sd8] = kpre[j];
        #pragma unroll
        for (int j = 0; j < 6; j++)
            *(float4*)&Pos[(srow + j * 32) * 72 + sd8] = ppre[j];
        __syncthreads();   // barrier A
        #pragma unroll
        for (int j = 0; j < 2; j++)
            *(float4*)&Vs[(srow + j * 32) * 72 + sd8] = vpre[j];
        {   // prefetch next tile
            int s0l = (it < 15) ? s0 + 64 : s0;
            int diffl = s0l - t0;
            int jbl = (diffl <= 64) ? (T_ - 128 + diffl) : (diffl - 129);
            #pragma unroll
            for (int j = 0; j < 2; j++)
                kpre[j] = *(const float4*)(kg + (size_t)(s0l + srow + j * 32) * 768 + sd8);
            #pragma unroll
            for (int j = 0; j < 6; j++){
                int jj = jbl + srow + j * 32;
                ppre[j] = ((unsigned)jj < (unsigned)T_)
                          ? *(const float4*)(pg + (size_t)jj * D_ + sd8)
                          : make_float4(0.f,0.f,0.f,0.f);
            }
            #pragma unroll
            for (int j = 0; j < 2; j++)
                vpre[j] = *(const float4*)(vtg + (size_t)(srow + j * 32) * T_ + s0l + sd8);
        }
        // ---- QK ----
        floatx4 S[2][4];
        #pragma unroll
        for (int a = 0; a < 2; a++)
            #pragma unroll
            for (int i = 0; i < 4; i++) S[a][i] = (floatx4){0.f,0.f,0.f,0.f};
        #pragma unroll
        for (int ks = 0; ks < 2; ks++){
            bhalf8 bf[4];
            #pragma unroll
            for (int nt = 0; nt < 4; nt++)
                bf[nt] = *(const bhalf8*)&Ks[(nt * 16 + ln15) * 72 + ks * 32 + quad * 8];
            #pragma unroll
            for (int a = 0; a < 2; a++)
                #pragma unroll
                for (int nt = 0; nt < 4; nt++)
                    S[a][nt] = __builtin_amdgcn_mfma_f32_16x16x32_bf16(quf[a][ks], bf[nt], S[a][nt], 0, 0, 0);
        }
        // ---- band (first pass) ----
        floatx4 Bacc[2][5];
        #pragma unroll
        for (int a = 0; a < 2; a++)
            #pragma unroll
            for (int i = 0; i < 5; i++) Bacc[a][i] = (floatx4){0.f,0.f,0.f,0.f};
        #pragma unroll
        for (int ks = 0; ks < 2; ks++)
            #pragma unroll
            for (int a = 0; a < 2; a++){
                bhalf8 av = doA ? qvf0[a][ks] : qvf1[a][ks];
                int ntlo = 7 - 2 * w - a;
                #pragma unroll
                for (int n5 = 0; n5 < 5; n5++){
                    bhalf8 bf = *(const bhalf8*)&Pos[((ntlo + n5) * 16 + ln15) * 72 + ks * 32 + quad * 8];
                    Bacc[a][n5] = __builtin_amdgcn_mfma_f32_16x16x32_bf16(av, bf, Bacc[a][n5], 0, 0, 0);
                }
            }
        if (doA && doB){   // mixed tile: restage band B, add with q[t+1]
            __syncthreads();
            int jbB = diff - 129;
            #pragma unroll
            for (int j = 0; j < 6; j++){
                int jj = jbB + srow + j * 32;
                float4 val = make_float4(0.f,0.f,0.f,0.f);
                if ((unsigned)jj < (unsigned)T_)
                    val = *(const float4*)(pg + (size_t)jj * D_ + sd8);
                *(float4*)&Pos[(srow + j * 32) * 72 + sd8] = val;
            }
            __syncthreads();
            #pragma unroll
            for (int ks = 0; ks < 2; ks++)
                #pragma unroll
                for (int a = 0; a < 2; a++){
                    int ntlo = 7 - 2 * w - a;
                    #pragma unroll
                    for (int n5 = 0; n5 < 5; n5++){
                        bhalf8 bf = *(const bhalf8*)&Pos[((ntlo + n5) * 16 + ln15) * 72 + ks * 32 + quad * 8];
                        Bacc[a][n5] = __builtin_amdgcn_mfma_f32_16x16x32_bf16(qvf1[a][ks], bf, Bacc[a][n5], 0, 0, 0);
                    }
                }
        }
        // ---- band strip ----
        #pragma unroll
        for (int a = 0; a < 2; a++)
            #pragma unroll
            for (int n5 = 0; n5 < 5; n5++)
                #pragma unroll
                for (int r = 0; r < 4; r++)
                    pbw[(a * 16 + quad * 4 + r) * 90 + n5 * 16 + ln15] = f2b_fast(Bacc[a][n5][r]);
        // ---- sc + online softmax (DPP) ----
        #pragma unroll
        for (int a = 0; a < 2; a++){
            float sc[4][4];
            #pragma unroll
            for (int nt = 0; nt < 4; nt++)
                #pragma unroll
                for (int r = 0; r < 4; r++)
                    sc[nt][r] = S[a][nt][r] +
                        b2f(pbw[(a * 16 + quad * 4 + r) * 90 + nt * 16 + ln15 + 15 - quad * 4 - r]);
            float p[4][4];
            #pragma unroll
            for (int r = 0; r < 4; r++){
                float rowm = fmaxf(fmaxf(sc[0][r], sc[1][r]), fmaxf(sc[2][r], sc[3][r]));
                rowm = dpp16_max(rowm);
                float mnew = fmaxf(m_r[a][r], rowm);
                float alpha = __expf(m_r[a][r] - mnew);
                float rs = 0.f;
                #pragma unroll
                for (int nt = 0; nt < 4; nt++){ p[nt][r] = __expf(sc[nt][r] - mnew); rs += p[nt][r]; }
                rs = dpp16_add(rs);
                l_r[a][r] = l_r[a][r] * alpha + rs;
                m_r[a][r] = mnew;
                O[a][0][r] *= alpha; O[a][1][r] *= alpha; O[a][2][r] *= alpha; O[a][3][r] *= alpha;
            }
            #pragma unroll
            for (int nt = 0; nt < 4; nt++)
                #pragma unroll
                for (int r = 0; r < 4; r++)
                    pbw[(a * 16 + quad * 4 + r) * 90 + nt * 16 + ln15] = f2b_fast(p[nt][r]);
        }
        __syncthreads();   // barrier B (Vs staged)
        // ---- PV ----
        #pragma unroll
        for (int ks = 0; ks < 2; ks++){
            bhalf8 bfv[4];
            #pragma unroll
            for (int nt = 0; nt < 4; nt++)
                bfv[nt] = *(const bhalf8*)&Vs[(nt * 16 + ln15) * 72 + ks * 32 + quad * 8];
            #pragma unroll
            for (int a = 0; a < 2; a++){
                bhalf8 af = *(const bhalf8*)&pbw[(a * 16 + ln15) * 90 + ks * 32 + quad * 8];
                #pragma unroll
                for (int nt = 0; nt < 4; nt++)
                    O[a][nt] = __builtin_amdgcn_mfma_f32_16x16x32_bf16(af, bfv[nt], O[a][nt], 0, 0, 0);
            }
        }
    }
    // ---- write partials ----
    #pragma unroll
    for (int a = 0; a < 2; a++)
        #pragma unroll
        for (int r = 0; r < 4; r++){
            int t = t0 + w * 32 + a * 16 + quad * 4 + r;
            size_t row = (size_t)(z * 32768 + bh * 2048 + t);
            #pragma unroll
            for (int nt = 0; nt < 4; nt++)
                Op[row * 64 + nt * 16 + ln15] = O[a][nt][r];
            if (ln15 == 0){
                ml[row * 2 + 0] = m_r[a][r];
                ml[row * 2 + 1] = l_r[a][r];
            }
        }
}

// ---------------- merge split-K attention partials ----------------
__global__ __launch_bounds__(256) void amerge_kernel(const float* __restrict__ Op,
        const float* __restrict__ ml, u16* __restrict__ ctx){
    int gid = blockIdx.x * 256 + threadIdx.x;
    int row = gid >> 4, d4 = (gid & 15) * 4;
    int bh = row >> 11, t = row & 2047;
    int b = bh >> 2, h = bh & 3;
    float m1 = ml[(size_t)row * 2], l1 = ml[(size_t)row * 2 + 1];
    float m2 = ml[(size_t)(32768 + row) * 2], l2 = ml[(size_t)(32768 + row) * 2 + 1];
    float m = fmaxf(m1, m2);
    float a1 = __expf(m1 - m), a2 = __expf(m2 - m);
    float invl = 1.f / (l1 * a1 + l2 * a2);
    float4 o1 = *(const float4*)(Op + (size_t)row * 64 + d4);
    float4 o2 = *(const float4*)(Op + (size_t)(32768 + row) * 64 + d4);
    ushort4 o;
    o.x = f2b((o1.x * a1 + o2.x * a2) * invl);
    o.y = f2b((o1.y * a1 + o2.y * a2) * invl);
    o.z = f2b((o1.z * a1 + o2.z * a2) * invl);
    o.w = f2b((o1.w * a1 + o2.w * a2) * invl);
    *(ushort4*)(ctx + ((size_t)(b * T_ + t)) * D_ + h * DH_ + d4) = o;
}

// ---------------- fused GLU + depthwise conv K=7 + GN stats ----------------
#define TT_ 32
__global__ __launch_bounds__(256) void dw3_kernel(const u16* __restrict__ yp,
        const float* __restrict__ w, const float* __restrict__ bias,
        float* __restrict__ y, float* __restrict__ stats){
    __shared__ u16 tile[(TT_ + 6) * INNER_];
    int tid = threadIdx.x;
    int t0 = blockIdx.x * TT_, b = blockIdx.y;
    for (int uu = tid; uu < (TT_ + 6) * 64; uu += 256){
        int row = uu >> 6, c8 = (uu & 63) * 8;
        int t = t0 + row - 3;
        u16 o8[8] = {0,0,0,0,0,0,0,0};
        if ((unsigned)t < (unsigned)T_){
            u16 a8[8], g8[8];
            const u16* rp = yp + ((size_t)(b * T_ + t)) * 1024;
            *(float4*)a8 = *(const float4*)(rp + c8);
            *(float4*)g8 = *(const float4*)(rp + 512 + c8);
            #pragma unroll
            for (int j = 0; j < 8; j++) o8[j] = f2b_fast(b2f(a8[j]) * lrelu(b2f(g8[j])));
        }
        *(float4*)&tile[row * INNER_ + c8] = *(float4*)o8;
    }
    __syncthreads();
    int c8 = (tid & 63) * 8, trow = tid >> 6;
    float wreg[7][8], bv[8];
    #pragma unroll
    for (int j = 0; j < 8; j++){
        bv[j] = bias[c8 + j];
        #pragma unroll
        for (int kk = 0; kk < 7; kk++) wreg[kk][j] = w[(c8 + j) * 7 + kk];
    }
    float s1 = 0.f, s2 = 0.f;
    for (int tt = trow; tt < TT_; tt += 4){
        float acc[8];
        #pragma unroll
        for (int j = 0; j < 8; j++) acc[j] = bv[j];
        #pragma unroll
        for (int kk = 0; kk < 7; kk++){
            u16 r8[8];
            *(float4*)r8 = *(const float4*)&tile[(tt + kk) * INNER_ + c8];
            #pragma unroll
            for (int j = 0; j < 8; j++) acc[j] += b2f(r8[j]) * wreg[kk][j];
        }
        float4 o0 = make_float4(acc[0], acc[1], acc[2], acc[3]);
        float4 o1 = make_float4(acc[4], acc[5], acc[6], acc[7]);
        float* ypt = y + ((size_t)(b * T_ + t0 + tt)) * INNER_ + c8;
        *(float4*)ypt = o0;
        *(float4*)(ypt + 4) = o1;
        #pragma unroll
        for (int j = 0; j < 8; j++){ s1 += acc[j]; s2 += acc[j] * acc[j]; }
    }
    #pragma unroll
    for (int mk = 1; mk < 64; mk <<= 1){
        s1 += __shfl_xor(s1, mk, 64);
        s2 += __shfl_xor(s2, mk, 64);
    }
    if ((tid & 63) == 0){
        atomicAdd(&stats[b * 2], s1);
        atomicAdd(&stats[b * 2 + 1], s2);
    }
}

// ---------------- GroupNorm(1) apply + leaky, bf16 out ----------------
__global__ __launch_bounds__(256) void gn_kernel(const float* __restrict__ y,
        const float* __restrict__ g, const float* __restrict__ b2,
        const float* __restrict__ stats, u16* __restrict__ out){
    int idx4 = (blockIdx.x * 256 + threadIdx.x) * 4;
    int b = idx4 / (T_ * INNER_);
    int i = idx4 & (INNER_ - 1);
    const float invN = 1.f / (float)(T_ * INNER_);
    float mean = stats[b * 2] * invN;
    float var  = stats[b * 2 + 1] * invN - mean * mean;
    float rs = rsqrtf(var + 1e-5f);
    float4 v = *(const float4*)(y + idx4);
    float4 gg = *(const float4*)(g + i);
    float4 bb = *(const float4*)(b2 + i);
    ushort4 o;
    o.x = f2b(lrelu((v.x - mean) * rs * gg.x + bb.x));
    o.y = f2b(lrelu((v.y - mean) * rs * gg.y + bb.y));
    o.z = f2b(lrelu((v.z - mean) * rs * gg.z + bb.z));
    o.w = f2b(lrelu((v.w - mean) * rs * gg.w + bb.w));
    *(ushort4*)(out + idx4) = o;
}

extern "C" void kernel_launch(void* const* d_in, const int* in_sizes, int n_in,
                              void* d_out, int out_size, void* d_ws, size_t ws_size,
                              hipStream_t stream){
    const float* x        = (const float*)d_in[0];
    const float* enc      = (const float*)d_in[1];
    const float* ff_ln_g  = (const float*)d_in[3];
    const float* ff_ln_b  = (const float*)d_in[4];
    const float* ff_w1    = (const float*)d_in[5];
    const float* ff_b1    = (const float*)d_in[6];
    const float* ff_w2    = (const float*)d_in[7];
    const float* ff_b2    = (const float*)d_in[8];
    const float* at_ln_g  = (const float*)d_in[9];
    const float* at_ln_b  = (const float*)d_in[10];
    const float* q_w      = (const float*)d_in[11];
    const float* q_b      = (const float*)d_in[12];
    const float* k_w      = (const float*)d_in[13];
    const float* v_w      = (const float*)d_in[14];
    const float* pos_w    = (const float*)d_in[15];
    const float* u_bias   = (const float*)d_in[16];
    const float* v_bias   = (const float*)d_in[17];
    const float* out_w    = (const float*)d_in[18];
    const float* out_b    = (const float*)d_in[19];
    const float* cm_ln_g  = (const float*)d_in[20];
    const float* cm_ln_b  = (const float*)d_in[21];
    const float* pw1_w    = (const float*)d_in[22];
    const float* pw1_b    = (const float*)d_in[23];
    const float* dw_w     = (const float*)d_in[24];
    const float* dw_b     = (const float*)d_in[25];
    const float* gn_g     = (const float*)d_in[26];
    const float* gn_b     = (const float*)d_in[27];
    const float* pw2_w    = (const float*)d_in[28];
    const float* pw2_b    = (const float*)d_in[29];
    float* out = (float*)d_out;

    char* ws = (char*)d_ws;
    u16*   y1bf = (u16*)(ws + 0);
    u16*   ypw1 = (u16*)(ws + 0);
    float* Op   = (float*)(ws + 0);
    float* ml   = (float*)(ws + ((size_t)16 << 20));
    float* ydw  = (float*)(ws + ((size_t)16 << 20));
    u16*   qkv  = (u16*)(ws + ((size_t)32 << 20));
    u16*   vbT  = (u16*)(ws + ((size_t)44 << 20));
    u16*   ctxb = (u16*)(ws + ((size_t)48 << 20));
    u16*   posb = (u16*)(ws + ((size_t)52 << 20));
    u16*   lnbuf= (u16*)(ws + ((size_t)53 << 20));
    float* x1   = (float*)(ws + ((size_t)57 << 20));
    float* x2   = (float*)(ws + ((size_t)65 << 20));
    u16*   gnb  = (u16*)(ws + ((size_t)36 << 20));
    char* W = ws + ((size_t)81 << 20);
    u16* ff1w  = (u16*)(W);
    u16* ff2w  = (u16*)(W + ((size_t)2 << 20));
    u16* qkvw  = (u16*)(W + ((size_t)3 << 20));
    u16* kw    = qkvw + 65536;
    u16* vw    = qkvw + 131072;
    u16* posw  = (u16*)(W + ((size_t)3 << 20) + (384u << 10));
    u16* outw  = (u16*)(W + ((size_t)4 << 20));
    u16* pw1w  = (u16*)(W + ((size_t)5 << 20));
    u16* pw2w  = (u16*)(W + ((size_t)6 << 20));
    u16* encb  = (u16*)(W + ((size_t)7 << 20));
    u16* zbuf  = (u16*)(W + ((size_t)8 << 20));
    float* stats    = (float*)(W + ((size_t)8 << 20) + 4096);
    float* qkv_bias = (float*)(W + ((size_t)8 << 20) + 8192);

    const int MBT = B_ * T_;

    hipMemsetAsync(W + ((size_t)8 << 20), 0, 16384, stream);
    hipMemcpyAsync(qkv_bias, q_b, 256 * sizeof(float), hipMemcpyDeviceToDevice, stream);
    cast4_kernel<<<dim3(2048, 4), 256, 0, stream>>>(
        ff_w2, ff2w, 256*1024, pw1_w, pw1w, 1024*256,
        pw2_w, pw2w, 256*512,  enc,   encb, 2048*256);
    castT5_kernel<<<dim3(256, 5), 256, 0, stream>>>(
        q_w, k_w, v_w, pos_w, out_w, qkvw, kw, vw, posw, outw);
    castFF1_kernel<<<3072, 256, 0, stream>>>(ff_w1, ff1w);

    // --- FeedForward ---
    ln_kernel<<<MBT/4, 256, 0, stream>>>(x, ff_ln_g, ff_ln_b, lnbuf);
    gemm_bf<128,1,true,true,false,true><<<dim3(FFI_/128, MBT/128), 256, 0, stream>>>(
        lnbuf, ff1w, ff_b1, nullptr, y1bf, MBT, FFI_, 3*D_, 0.f, zbuf);
    gemm_bf<64,0,true,false,true,false><<<dim3(D_/64, MBT/128), 256, 0, stream>>>(
        y1bf, ff2w, ff_b2, x, x1, MBT, D_, FFI_, 0.5f, nullptr);

    // --- Relative MHSA ---
    ln_kernel<<<MBT/4, 256, 0, stream>>>(x1, at_ln_g, at_ln_b, lnbuf);
    gemm_bf<64,0,true,false,false,true><<<dim3(768/64, MBT/128), 256, 0, stream>>>(
        lnbuf, qkvw, qkv_bias, nullptr, qkv, MBT, 768, D_, 0.f, nullptr);
    gemm_bf<64,0,false,false,false,true><<<dim3(D_/64, T_/128), 256, 0, stream>>>(
        encb, posw, nullptr, nullptr, posb, T_, D_, D_, 0.f, nullptr);
    vT_kernel<<<dim3(T_/64, D_/64, B_), 256, 0, stream>>>(qkv, vbT);
    attn8_kernel<<<dim3(T_/128, B_*H_, 2), 256, 0, stream>>>(
        qkv, vbT, posb, u_bias, v_bias, Op, ml);
    amerge_kernel<<<(32768 * 16) / 256, 256, 0, stream>>>(Op, ml, ctxb);
    gemm_bf<64,0,true,false,true,false><<<dim3(D_/64, MBT/128), 256, 0, stream>>>(
        ctxb, outw, out_b, x1, x2, MBT, D_, D_, 1.f, nullptr);

    // --- Conformer conv module ---
    ln_kernel<<<MBT/4, 256, 0, stream>>>(x2, cm_ln_g, cm_ln_b, lnbuf);
    gemm_bf<128,0,true,false,false,true><<<dim3(FFI_/128, MBT/128), 256, 0, stream>>>(
        lnbuf, pw1w, pw1_b, nullptr, ypw1, MBT, FFI_, D_, 0.f, nullptr);
    dw3_kernel<<<dim3(T_/TT_, B_), 256, 0, stream>>>(ypw1, dw_w, dw_b, ydw, stats);
    gn_kernel<<<(MBT * INNER_) / (256 * 4), 256, 0, stream>>>(ydw, gn_g, gn_b, stats, gnb);
    gemm_bf<64,0,true,false,true,false><<<dim3(D_/64, MBT/128), 256, 0, stream>>>(
        gnb, pw2w, pw2_b, x2, out, MBT, D_, INNER_, 1.f, nullptr);
}